// Round 3
// baseline (354.238 us; speedup 1.0000x reference)
//
#include <hip/hip_runtime.h>
#include <math.h>

// Problem constants (from reference setup_inputs)
constexpr int kB  = 32;
constexpr int kS  = 4096;
constexpr int kH  = 1024;
constexpr int kNC = 128;          // S-chunks per batch
constexpr int kCH = kS / kNC;     // 32 rows per chunk
constexpr int WPB = 4;            // waves per block (256 threads)

// One context row as held by one lane: float4 at h = 4*lane + 256*k, k=0..3
struct Row { float4 a, b, c, d; };

__device__ __forceinline__ Row load_row(const float4* __restrict__ p) {
  Row r; r.a = p[0]; r.b = p[64]; r.c = p[128]; r.d = p[192]; return r;
}

__device__ __forceinline__ float dot_row(const Row& w, const Row& q) {
  float s;
  s  = w.a.x*q.a.x + w.a.y*q.a.y + w.a.z*q.a.z + w.a.w*q.a.w;
  s += w.b.x*q.b.x + w.b.y*q.b.y + w.b.z*q.b.z + w.b.w*q.b.w;
  s += w.c.x*q.c.x + w.c.y*q.c.y + w.c.z*q.c.z + w.c.w*q.c.w;
  s += w.d.x*q.d.x + w.d.y*q.d.y + w.d.z*q.d.z + w.d.w*q.d.w;
  return s;
}

// acc4 = acc4*sc + p0*w04 + p1*w14   (1 mul + 2 fma per element)
#define PAIR4(acc4, w04, w14) \
  acc4.x = fmaf(p1, w14.x, fmaf(p0, w04.x, acc4.x * sc)); \
  acc4.y = fmaf(p1, w14.y, fmaf(p0, w04.y, acc4.y * sc)); \
  acc4.z = fmaf(p1, w14.z, fmaf(p0, w04.z, acc4.z * sc)); \
  acc4.w = fmaf(p1, w14.w, fmaf(p0, w04.w, acc4.w * sc));

// ---------------------------------------------------------------------------
// Pass 1: one wave per (batch, chunk). Flash-style online softmax over the
// chunk's 32 context rows, processed in BRANCHLESS pairs. Two rows resident
// (v0,v1) + two working copies (w0,w1): loads for the next pair are issued
// at the TOP of each iteration (no control flow between issue and compute),
// and the two butterfly reduce chains interleave (2 independent DS chains).
// Peak ~112 VGPR -> fits the 128-cap from __launch_bounds__(256,4).
// ---------------------------------------------------------------------------
__global__ __launch_bounds__(256, 4) void attn_pass1(
    const float* __restrict__ q,      // [B, H]
    const float* __restrict__ ctx,    // [B, S, H]
    float* __restrict__ scores,       // [B, S]   raw logits
    float* __restrict__ pm,           // [B*NC]
    float* __restrict__ pl,           // [B*NC]
    float* __restrict__ pacc)         // [B*NC, H]
{
  const int lane = threadIdx.x & 63;
  const int wid  = threadIdx.x >> 6;
  const int wave = blockIdx.x * WPB + wid;   // 0 .. B*NC-1
  const int b    = wave / kNC;
  const int c    = wave % kNC;

  const float4* qp = reinterpret_cast<const float4*>(q + (size_t)b * kH) + lane;
  const Row Q = load_row(qp);

  const float4* cp =
      reinterpret_cast<const float4*>(ctx + ((size_t)b * kS + (size_t)c * kCH) * kH) + lane;

  float m = -3.0e38f, l = 0.0f;
  Row acc; acc.a = make_float4(0.f,0.f,0.f,0.f); acc.b = acc.a; acc.c = acc.a; acc.d = acc.a;
  float myscore = 0.0f;

  // prologue: rows 0,1 in flight
  Row v0 = load_row(cp + 0 * 256);
  Row v1 = load_row(cp + 1 * 256);

  #pragma unroll
  for (int r = 0; r < kCH; r += 2) {
    const Row w0 = v0, w1 = v1;
    if (r + 2 < kCH) {           // issue next pair BEFORE any compute
      v0 = load_row(cp + (size_t)(r + 2) * 256);
      v1 = load_row(cp + (size_t)(r + 3) * 256);
    }

    float d0 = dot_row(w0, Q);
    float d1 = dot_row(w1, Q);
    // two interleaved butterfly chains (independent DS ops overlap)
    #pragma unroll
    for (int off = 32; off >= 1; off >>= 1) {
      d0 += __shfl_xor(d0, off, 64);
      d1 += __shfl_xor(d1, off, 64);
    }

    if (lane == r)     myscore = d0;
    if (lane == r + 1) myscore = d1;

    // branchless pair update (single rescale per pair)
    const float nm = fmaxf(m, fmaxf(d0, d1));
    const float sc = __expf(m - nm);      // first iter: exp(-inf) == 0
    const float p0 = __expf(d0 - nm);
    const float p1 = __expf(d1 - nm);
    m = nm;
    l = fmaf(l, sc, p0 + p1);
    PAIR4(acc.a, w0.a, w1.a);
    PAIR4(acc.b, w0.b, w1.b);
    PAIR4(acc.c, w0.c, w1.c);
    PAIR4(acc.d, w0.d, w1.d);
  }

  // epilogue: coalesced stores
  if (lane < kCH) scores[(size_t)b * kS + (size_t)c * kCH + lane] = myscore;
  if (lane == 0) { pm[wave] = m; pl[wave] = l; }
  float4* pap = reinterpret_cast<float4*>(pacc + (size_t)wave * kH) + lane;
  pap[0] = acc.a; pap[64] = acc.b; pap[128] = acc.c; pap[192] = acc.d;
}

// ---------------------------------------------------------------------------
// Pass 2: grid (B, 9). Every block recomputes global (m_g, inv) from the 128
// chunk partials. Blocks by=0..7 each combine one 128-wide h slice of the
// acc partials (float4 loads, unroll 16, 8 i-stripes combined via LDS) and
// write out = tanh(acc*inv). Block by=8 normalizes raw logits into attn.
// d_out layout: [out (B*H floats)] ++ [attn (B*S floats)]
// ---------------------------------------------------------------------------
__global__ __launch_bounds__(256) void attn_pass2(
    const float* __restrict__ scores,
    const float* __restrict__ pm,
    const float* __restrict__ pl,
    const float* __restrict__ pacc,
    float* __restrict__ out)
{
  const int b  = blockIdx.x;
  const int by = blockIdx.y;
  const int t  = threadIdx.x;

  __shared__ float red[256];
  __shared__ float wgt[kNC];
  __shared__ float4 sh4[8][32];

  // global max over this batch's chunk maxima
  const float mi = (t < kNC) ? pm[b * kNC + t] : -3.0e38f;
  red[t] = mi;
  __syncthreads();
  #pragma unroll
  for (int o = 128; o >= 1; o >>= 1) {
    if (t < o) red[t] = fmaxf(red[t], red[t + o]);
    __syncthreads();
  }
  const float m_g = red[0];
  __syncthreads();

  // per-chunk rescale weights + global denom
  float li = 0.0f;
  if (t < kNC) {
    const float wi = __expf(mi - m_g);
    wgt[t] = wi;
    li = pl[b * kNC + t] * wi;
  }
  red[t] = li;
  __syncthreads();
  #pragma unroll
  for (int o = 128; o >= 1; o >>= 1) {
    if (t < o) red[t] += red[t + o];
    __syncthreads();
  }
  const float inv = 1.0f / red[0];
  __syncthreads();

  if (by < 8) {
    // combine acc partials for h in [by*128, by*128+128)
    const int h4     = t & 31;   // float4 index within the slice
    const int stripe = t >> 5;   // 8 i-stripes
    const float4* base =
        reinterpret_cast<const float4*>(pacc + ((size_t)(b * kNC + stripe)) * kH + by * 128) + h4;
    const size_t istep = (size_t)8 * (kH / 4);  // i += 8, in float4 units

    float4 s = make_float4(0.f, 0.f, 0.f, 0.f);
    #pragma unroll 16
    for (int k = 0; k < 16; ++k) {
      const float w = wgt[stripe + 8 * k];
      const float4 v = base[(size_t)k * istep];
      s.x = fmaf(w, v.x, s.x); s.y = fmaf(w, v.y, s.y);
      s.z = fmaf(w, v.z, s.z); s.w = fmaf(w, v.w, s.w);
    }
    sh4[stripe][h4] = s;
    __syncthreads();

    if (t < 32) {
      float4 r = sh4[0][t];
      #pragma unroll
      for (int i = 1; i < 8; ++i) {
        const float4 v = sh4[i][t];
        r.x += v.x; r.y += v.y; r.z += v.z; r.w += v.w;
      }
      r.x = tanhf(r.x * inv); r.y = tanhf(r.y * inv);
      r.z = tanhf(r.z * inv); r.w = tanhf(r.w * inv);
      reinterpret_cast<float4*>(out + (size_t)b * kH + by * 128)[t] = r;
    }
  } else {
    // normalize logits -> attn (float4, coalesced)
    const float4* sb = reinterpret_cast<const float4*>(scores + (size_t)b * kS);
    float4* ab = reinterpret_cast<float4*>(out + (size_t)kB * kH + (size_t)b * kS);
    #pragma unroll
    for (int k = 0; k < kS / 4 / 256; ++k) {
      const int i = k * 256 + t;
      float4 v = sb[i];
      v.x = __expf(v.x - m_g) * inv; v.y = __expf(v.y - m_g) * inv;
      v.z = __expf(v.z - m_g) * inv; v.w = __expf(v.w - m_g) * inv;
      ab[i] = v;
    }
  }
}

extern "C" void kernel_launch(void* const* d_in, const int* in_sizes, int n_in,
                              void* d_out, int out_size, void* d_ws, size_t ws_size,
                              hipStream_t stream) {
  const float* q   = (const float*)d_in[0];   // output: (B,1,H) fp32 — the query
  const float* ctx = (const float*)d_in[1];   // context: (B,S,H) fp32
  float* out = (float*)d_out;
  float* ws  = (float*)d_ws;

  // workspace layout (floats): scores[B*S] | pm[B*NC] | pl[B*NC] | pacc[B*NC*H]
  float* scores = ws;
  float* pm     = scores + (size_t)kB * kS;
  float* pl     = pm + kB * kNC;
  float* pacc   = pl + kB * kNC;   // offset 139264 floats -> 16B aligned

  attn_pass1<<<dim3(kB * kNC / WPB), 256, 0, stream>>>(q, ctx, scores, pm, pl, pacc);
  attn_pass2<<<dim3(kB, 9), 256, 0, stream>>>(scores, pm, pl, pacc, out);
}

// Round 4
// 115.217 us; speedup vs baseline: 3.0745x; 3.0745x over previous
//
#include <hip/hip_runtime.h>
#include <math.h>

// Problem constants (from reference setup_inputs)
constexpr int kB  = 32;
constexpr int kS  = 4096;
constexpr int kH  = 1024;
constexpr int kNC = 128;          // S-chunks per batch
constexpr int kCH = kS / kNC;     // 32 rows per chunk
constexpr int WPB = 4;            // waves per block (256 threads)
constexpr int NP  = kCH / 2;      // 16 row-pairs per chunk

// async global->LDS, 16B per lane (64 lanes -> 1KB per instruction).
// LDS dest is wave-uniform base + lane*16 (HW adds the lane offset).
#define GLOAD_LDS16(gp, lp)                                                        \
  __builtin_amdgcn_global_load_lds(                                               \
      (const __attribute__((address_space(1))) void*)(gp),                        \
      (__attribute__((address_space(3))) void*)(lp), 16, 0, 0)

// Stage one 1024-float context row into LDS (4 x 1KB quarters).
__device__ __forceinline__ void stage_row(const float* __restrict__ g,
                                          float* l, int lane) {
  #pragma unroll
  for (int j = 0; j < 4; ++j)
    GLOAD_LDS16(g + j * 256 + 4 * lane, l + j * 256);
}

// acc4 = acc4*sc + p0*w04 + p1*w14
#define PAIR4(acc4, w04, w14) \
  acc4.x = fmaf(p1, w14.x, fmaf(p0, w04.x, acc4.x * sc)); \
  acc4.y = fmaf(p1, w14.y, fmaf(p0, w04.y, acc4.y * sc)); \
  acc4.z = fmaf(p1, w14.z, fmaf(p0, w04.z, acc4.z * sc)); \
  acc4.w = fmaf(p1, w14.w, fmaf(p0, w04.w, acc4.w * sc));

// ---------------------------------------------------------------------------
// Pass 1: one wave per (batch, chunk). Context rows stream through a
// per-wave PRIVATE double-buffered LDS tile via global_load_lds (no dest
// VGPRs -> prefetch depth is controlled by explicit vmcnt, not the register
// allocator). No __syncthreads needed (buffers are wave-private).
// ---------------------------------------------------------------------------
__global__ __launch_bounds__(256, 2) void attn_pass1(
    const float* __restrict__ q,      // [B, H]
    const float* __restrict__ ctx,    // [B, S, H]
    float* __restrict__ scores,       // [B, S]   raw logits
    float* __restrict__ pm,           // [B*NC]
    float* __restrict__ pl,           // [B*NC]
    float* __restrict__ pacc)         // [B*NC, H]
{
  // per wave: 2 buffers x 2 rows x 1024 floats = 16 KB; 4 waves = 64 KB
  __shared__ __align__(16) float lds[WPB * 2 * 2048];

  const int lane = threadIdx.x & 63;
  const int wid  = threadIdx.x >> 6;
  const int wave = blockIdx.x * WPB + wid;   // 0 .. B*NC-1
  const int b    = wave / kNC;
  const int c    = wave % kNC;

  float* wbuf = &lds[wid * 4096];

  const float4* qp = reinterpret_cast<const float4*>(q + (size_t)b * kH) + lane;
  const float4 Qa = qp[0], Qb = qp[64], Qc = qp[128], Qd = qp[192];

  const float* cbase = ctx + ((size_t)b * kS + (size_t)c * kCH) * kH;

  float m = -3.0e38f, l = 0.0f;
  float4 aa = make_float4(0.f,0.f,0.f,0.f), ab = aa, ac = aa, ad = aa;
  float myscore = 0.0f;

  // prologue: stage pair 0 into buffer 0 (8 loads in flight)
  stage_row(cbase,        wbuf,        lane);
  stage_row(cbase + 1024, wbuf + 1024, lane);

  auto compute_pair = [&](int t) {
    const float4* p0 = reinterpret_cast<const float4*>(wbuf + (t & 1) * 2048) + lane;
    const float4* p1 = p0 + 256;   // second row of the pair (1024 floats)

    const float4 w0a = p0[0], w0b = p0[64], w0c = p0[128], w0d = p0[192];
    const float4 w1a = p1[0], w1b = p1[64], w1c = p1[128], w1d = p1[192];

    float d0, d1;
    d0  = w0a.x*Qa.x + w0a.y*Qa.y + w0a.z*Qa.z + w0a.w*Qa.w;
    d0 += w0b.x*Qb.x + w0b.y*Qb.y + w0b.z*Qb.z + w0b.w*Qb.w;
    d0 += w0c.x*Qc.x + w0c.y*Qc.y + w0c.z*Qc.z + w0c.w*Qc.w;
    d0 += w0d.x*Qd.x + w0d.y*Qd.y + w0d.z*Qd.z + w0d.w*Qd.w;
    d1  = w1a.x*Qa.x + w1a.y*Qa.y + w1a.z*Qa.z + w1a.w*Qa.w;
    d1 += w1b.x*Qb.x + w1b.y*Qb.y + w1b.z*Qb.z + w1b.w*Qb.w;
    d1 += w1c.x*Qc.x + w1c.y*Qc.y + w1c.z*Qc.z + w1c.w*Qc.w;
    d1 += w1d.x*Qd.x + w1d.y*Qd.y + w1d.z*Qd.z + w1d.w*Qd.w;

    // two interleaved butterfly chains
    #pragma unroll
    for (int off = 32; off >= 1; off >>= 1) {
      d0 += __shfl_xor(d0, off, 64);
      d1 += __shfl_xor(d1, off, 64);
    }

    if (lane == 2 * t)     myscore = d0;
    if (lane == 2 * t + 1) myscore = d1;

    // branchless online-softmax pair update
    const float nm = fmaxf(m, fmaxf(d0, d1));
    const float sc = __expf(m - nm);          // first pair: exp(-inf) == 0
    const float p0s = __expf(d0 - nm);
    const float p1s = __expf(d1 - nm);
    m = nm;
    l = fmaf(l, sc, p0s + p1s);
    { const float p0 = p0s, p1 = p1s;
      PAIR4(aa, w0a, w1a); PAIR4(ab, w0b, w1b);
      PAIR4(ac, w0c, w1c); PAIR4(ad, w0d, w1d); }
  };

  for (int t = 0; t < NP - 1; ++t) {
    // issue next pair's 8 DMA loads into the other buffer
    const float* g   = cbase + (size_t)(t + 1) * 2048;
    float*       lb  = wbuf + ((t + 1) & 1) * 2048;
    stage_row(g,        lb,        lane);
    stage_row(g + 1024, lb + 1024, lane);
    // wait until only the 8 just-issued remain -> pair t has landed
    asm volatile("s_waitcnt vmcnt(8)" ::: "memory");
    compute_pair(t);
  }
  asm volatile("s_waitcnt vmcnt(0)" ::: "memory");
  compute_pair(NP - 1);

  // epilogue: coalesced stores
  if (lane < kCH) scores[(size_t)b * kS + (size_t)c * kCH + lane] = myscore;
  if (lane == 0) { pm[wave] = m; pl[wave] = l; }
  float4* pap = reinterpret_cast<float4*>(pacc + (size_t)wave * kH) + lane;
  pap[0] = aa; pap[64] = ab; pap[128] = ac; pap[192] = ad;
}

// ---------------------------------------------------------------------------
// Pass 2: grid (B, 9). Every block recomputes global (m_g, inv) from the 128
// chunk partials. Blocks by=0..7 each combine one 128-wide h slice of the
// acc partials (float4 loads, unroll 16, 8 i-stripes combined via LDS) and
// write out = tanh(acc*inv). Block by=8 normalizes raw logits into attn.
// d_out layout: [out (B*H floats)] ++ [attn (B*S floats)]
// ---------------------------------------------------------------------------
__global__ __launch_bounds__(256) void attn_pass2(
    const float* __restrict__ scores,
    const float* __restrict__ pm,
    const float* __restrict__ pl,
    const float* __restrict__ pacc,
    float* __restrict__ out)
{
  const int b  = blockIdx.x;
  const int by = blockIdx.y;
  const int t  = threadIdx.x;

  __shared__ float red[256];
  __shared__ float wgt[kNC];
  __shared__ float4 sh4[8][32];

  // global max over this batch's chunk maxima
  const float mi = (t < kNC) ? pm[b * kNC + t] : -3.0e38f;
  red[t] = mi;
  __syncthreads();
  #pragma unroll
  for (int o = 128; o >= 1; o >>= 1) {
    if (t < o) red[t] = fmaxf(red[t], red[t + o]);
    __syncthreads();
  }
  const float m_g = red[0];
  __syncthreads();

  // per-chunk rescale weights + global denom
  float li = 0.0f;
  if (t < kNC) {
    const float wi = __expf(mi - m_g);
    wgt[t] = wi;
    li = pl[b * kNC + t] * wi;
  }
  red[t] = li;
  __syncthreads();
  #pragma unroll
  for (int o = 128; o >= 1; o >>= 1) {
    if (t < o) red[t] += red[t + o];
    __syncthreads();
  }
  const float inv = 1.0f / red[0];
  __syncthreads();

  if (by < 8) {
    // combine acc partials for h in [by*128, by*128+128)
    const int h4     = t & 31;   // float4 index within the slice
    const int stripe = t >> 5;   // 8 i-stripes
    const float4* base =
        reinterpret_cast<const float4*>(pacc + ((size_t)(b * kNC + stripe)) * kH + by * 128) + h4;
    const size_t istep = (size_t)8 * (kH / 4);  // i += 8, in float4 units

    float4 s = make_float4(0.f, 0.f, 0.f, 0.f);
    #pragma unroll 16
    for (int k = 0; k < 16; ++k) {
      const float w = wgt[stripe + 8 * k];
      const float4 v = base[(size_t)k * istep];
      s.x = fmaf(w, v.x, s.x); s.y = fmaf(w, v.y, s.y);
      s.z = fmaf(w, v.z, s.z); s.w = fmaf(w, v.w, s.w);
    }
    sh4[stripe][h4] = s;
    __syncthreads();

    if (t < 32) {
      float4 r = sh4[0][t];
      #pragma unroll
      for (int i = 1; i < 8; ++i) {
        const float4 v = sh4[i][t];
        r.x += v.x; r.y += v.y; r.z += v.z; r.w += v.w;
      }
      r.x = tanhf(r.x * inv); r.y = tanhf(r.y * inv);
      r.z = tanhf(r.z * inv); r.w = tanhf(r.w * inv);
      reinterpret_cast<float4*>(out + (size_t)b * kH + by * 128)[t] = r;
    }
  } else {
    // normalize logits -> attn (float4, coalesced)
    const float4* sb = reinterpret_cast<const float4*>(scores + (size_t)b * kS);
    float4* ab = reinterpret_cast<float4*>(out + (size_t)kB * kH + (size_t)b * kS);
    #pragma unroll
    for (int k = 0; k < kS / 4 / 256; ++k) {
      const int i = k * 256 + t;
      float4 v = sb[i];
      v.x = __expf(v.x - m_g) * inv; v.y = __expf(v.y - m_g) * inv;
      v.z = __expf(v.z - m_g) * inv; v.w = __expf(v.w - m_g) * inv;
      ab[i] = v;
    }
  }
}

extern "C" void kernel_launch(void* const* d_in, const int* in_sizes, int n_in,
                              void* d_out, int out_size, void* d_ws, size_t ws_size,
                              hipStream_t stream) {
  const float* q   = (const float*)d_in[0];   // output: (B,1,H) fp32 — the query
  const float* ctx = (const float*)d_in[1];   // context: (B,S,H) fp32
  float* out = (float*)d_out;
  float* ws  = (float*)d_ws;

  // workspace layout (floats): scores[B*S] | pm[B*NC] | pl[B*NC] | pacc[B*NC*H]
  float* scores = ws;
  float* pm     = scores + (size_t)kB * kS;
  float* pl     = pm + kB * kNC;
  float* pacc   = pl + kB * kNC;   // offset 139264 floats -> 16B aligned

  attn_pass1<<<dim3(kB * kNC / WPB), 256, 0, stream>>>(q, ctx, scores, pm, pl, pacc);
  attn_pass2<<<dim3(kB, 9), 256, 0, stream>>>(scores, pm, pl, pacc, out);
}